// Round 7
// baseline (362.562 us; speedup 1.0000x reference)
//
#include <hip/hip_runtime.h>

// S_GC_att_A round 11: full __syncthreads restored + wf software-pipelined 1 iter ahead.
// R10 post-mortem (RACE): lgkmcnt-only barrier diverged under replay. Zw = p?Zs1:Zs0
// is a pointer SELECT; if addrspace inference keeps accesses generic they lower to
// flat ops whose visibility isn't guaranteed by lgkmcnt(0) alone. Unwinnable from
// source -> revert to __syncthreads everywhere (R9 semantics, which passed).
// The diagnosis stands: barrier vmcnt(0) drain is costly only because wf(k) issues
// right before barrier(k) with only the z-phase as cover. R11 moves the ISSUE POINT:
// wf(k+1) issues inside main(k) (after barrier k), so at barrier(k+1) it has all of
// main(k)'s 24 MFMAs + z(k+1) as cover -> drain ~free. Pure register pipeline,
// barrier semantics untouched. +16 VGPR (wfn beside wfc) at the 128-reg/4-wave
// boundary enforced by bounds(512,4). setprio(1) kept around the pure-MFMA cluster.
// Tripwires: WRITE_SIZE >> 101MB or dur regress => spill => pipeline only s=0 half.

#define TT    4
#define NTW   88     // TT*22
#define XSTR  104    // Xs row stride in bf16 (4*24 + 8 pad)
#define MROWS 176    // 7*24 + 8 pad rows
#define CHUNK 64
#define WB_BYTES (7 * 256 * 256 * 2)

typedef __attribute__((ext_vector_type(8))) __bf16    bf16x8;
typedef __attribute__((ext_vector_type(4))) float     f32x4;
typedef __attribute__((ext_vector_type(8))) short     s16x8;
typedef __attribute__((ext_vector_type(2))) unsigned  u32x2;
typedef __attribute__((ext_vector_type(4))) unsigned  u32x4;

__device__ __forceinline__ unsigned short f2bf_rn(float f) {  // RNE
  union { float f; unsigned u; } x; x.f = f;
  return (unsigned short)((x.u + 0x7FFFu + ((x.u >> 16) & 1u)) >> 16);
}
__device__ __forceinline__ unsigned pk_rh(float a, float b) { // lo=bf(a), hi=bf(b), half-up
  unsigned ua = __builtin_bit_cast(unsigned, a) + 0x8000u;
  unsigned ub = __builtin_bit_cast(unsigned, b) + 0x8000u;
  return __builtin_amdgcn_perm(ub, ua, 0x07060302);           // one v_perm_b32
}

// ---- W fp32 -> bf16 (RNE) into workspace; 224*256*8 = 458752 elems exact
__global__ void wconv(const float* __restrict__ W, unsigned short* __restrict__ Wb) {
  int i = (blockIdx.x * 256 + threadIdx.x) * 8;
  float4 a = *(const float4*)(W + i);
  float4 c = *(const float4*)(W + i + 4);
  s16x8 r;
  r[0] = (short)f2bf_rn(a.x); r[1] = (short)f2bf_rn(a.y);
  r[2] = (short)f2bf_rn(a.z); r[3] = (short)f2bf_rn(a.w);
  r[4] = (short)f2bf_rn(c.x); r[5] = (short)f2bf_rn(c.y);
  r[6] = (short)f2bf_rn(c.z); r[7] = (short)f2bf_rn(c.w);
  *(s16x8*)(Wb + i) = r;
}

__device__ __forceinline__ bf16x8 ldw_f32(const float* p) {   // fallback path
  float4 a = *(const float4*)(p);
  float4 c = *(const float4*)(p + 4);
  u32x4 q;
  q[0] = pk_rh(a.x, a.y); q[1] = pk_rh(a.z, a.w);
  q[2] = pk_rh(c.x, c.y); q[3] = pk_rh(c.z, c.w);
  return __builtin_bit_cast(bf16x8, q);
}

template <bool USE_WB>
__global__ __launch_bounds__(512, 4)
void sgc_fused(const float* __restrict__ x, const float* __restrict__ Ag,
               const float* __restrict__ attA, const float* __restrict__ W,
               const unsigned short* __restrict__ Wb, const float* __restrict__ b,
               float* __restrict__ out) {
  const int bx   = blockIdx.x;
  const int n    = bx & 7;            // XCD == n (x-tile L2 sharing across tt)
  const int tt   = bx >> 3;           // 0..127  (t-tile of 4)
  const int tid  = threadIdx.x;
  const int wave = tid >> 6;          // 0..7
  const int lane = tid & 63;
  const int l15  = lane & 15;
  const int l4   = lane >> 4;
  const int g    = wave & 3;          // z-phase ci-group
  const int h    = wave >> 2;         // z-phase t-half

  // LDS: Xs [64][104] bf16 @0 (13312) | Zs0 [96][64] swz @13312 (12288)
  //      Zs1 @25600 (12288) | Ms [176][32] bf16 @37888 (11264) | Ss @49152 (672)
  //      total 49824 B; 2 blocks/CU -> 99.6KB < 160KB
  __shared__ __align__(16) char smem[49824];
  unsigned short* Xs  = (unsigned short*)(smem);
  unsigned short* Zs0 = (unsigned short*)(smem + 13312);
  unsigned short* Zs1 = (unsigned short*)(smem + 25600);
  unsigned short* Ms  = (unsigned short*)(smem + 37888);
  float*          Ss  = (float*)(smem + 49152);
  float*          B2  = (float*)(smem);          // epilogue reuse: [256][25] f32 = 25600 B
                                                 // (covers Xs+Zs0; last main reads Zs1 - disjoint)

  f32x4 acc[2][6];                               // 48 AGPRs
  #pragma unroll
  for (int i = 0; i < 2; ++i)
    #pragma unroll
    for (int j = 0; j < 6; ++j)
      acc[i][j] = (f32x4){0.f, 0.f, 0.f, 0.f};

  auto load_wf = [&](bf16x8 (&wf)[2][2], int kk, int cc) {
    #pragma unroll
    for (int s = 0; s < 2; ++s)
      #pragma unroll
      for (int mi = 0; mi < 2; ++mi) {
        int c = wave * 32 + mi * 16 + l15;
        size_t idx = (size_t)((kk * 256 + c) * 256) + cc * CHUNK + s * 32 + l4 * 8;
        wf[s][mi] = USE_WB ? *(const bf16x8*)(Wb + idx) : ldw_f32(W + idx);
      }
  };

  // ---- block init: M~[k][w][v] = M_k[v][w] bf16, zero-padded ----
  for (int i = tid; i < MROWS * 32; i += 512) {
    int row = i >> 5, v = i & 31;
    int k = row / 24, w = row - k * 24;
    float val = 0.f;
    if (row < 168 && w < 22 && v < 22)
      val = (k < 3) ? Ag[(k * 22 + v) * 22 + w]
                    : attA[(((n << 2) + (k - 3)) * 22 + v) * 22 + w];
    Ms[i] = f2bf_rn(val);
  }
  if (tid < 168) {                               // S[k][w] = sum_v M_k[v][w] (fp32 exact)
    int k = tid / 24, w = tid - k * 24;
    float s = 0.f;
    if (w < 22)
      for (int v = 0; v < 22; ++v)
        s += (k < 3) ? Ag[(k * 22 + v) * 22 + w]
                     : attA[(((n << 2) + (k - 3)) * 22 + v) * 22 + w];
    Ss[tid] = s;
  }
  Zs0[88 * CHUNK + tid] = 0;                     // pad rows 88..95, both buffers
  Zs1[88 * CHUNK + tid] = 0;
  for (int i = tid; i < 64 * XSTR / 2; i += 512) ((unsigned*)Xs)[i] = 0; // pads 0, not NaN
  __syncthreads();

  const int ci0 = g * 16 + l4 * 4;               // z-output row this thread owns
  const int cb  = ci0 >> 3, sub = ci0 & 7;
  int p = 0;                                     // Zs parity

  // ---- wf pipeline prologue: iter (chunk0,k0) issued here; in flight through the
  //      whole chunk-0 staging (long cover) before its drain at the staging barrier.
  bf16x8 wfc[2][2];
  load_wf(wfc, 0, 0);

  for (int chunk = 0; chunk < 4; ++chunk) {
    // ---- stage x[n, chunk*64..+64, tt*4..+4, :] -> Xs bf16 [ci][t*24+v] ----
    // paired u32 writes: tv pairs at even offsets never straddle a t-row (22 even).
    for (int i = tid; i < CHUNK * 22; i += 512) {
      int ci = i / 22, q = i - ci * 22;
      const float4 f4 = *(const float4*)(x + (size_t)((n * 256 + chunk * CHUNK + ci) * 11264)
                                           + tt * NTW + q * 4);
      int tv0 = q * 4;
      int t0 = tv0 / 22, v0 = tv0 - t0 * 22;
      ((unsigned*)Xs)[ci * 52 + t0 * 12 + (v0 >> 1)] = pk_rh(f4.x, f4.y);
      int tv2 = tv0 + 2;
      int t2 = tv2 / 22, v2 = tv2 - t2 * 22;
      ((unsigned*)Xs)[ci * 52 + t2 * 12 + (v2 >> 1)] = pk_rh(f4.z, f4.w);
    }
    __syncthreads();

    for (int k = 0; k < 7; ++k) {
      unsigned short* Zw = p ? Zs1 : Zs0;

      // ---- z phase: z[ci,w] = X[ci,v] @ M_k[v,w]; wave (g,h): rows [g*16,+16),
      //      t in {2h, 2h+1}. 8 waves cover all 64 ci x 4 t exactly once. ----
      bf16x8 bm0 = *(const bf16x8*)(&Ms[(k * 24 + l15) * 32 + l4 * 8]);
      bf16x8 bm1 = *(const bf16x8*)(&Ms[(k * 24 + 16 + l15) * 32 + l4 * 8]);
      f32x4 zt[2][2];
      #pragma unroll
      for (int t2 = 0; t2 < 2; ++t2) {
        int t = h * 2 + t2;
        bf16x8 ax = *(const bf16x8*)(&Xs[(g * 16 + l15) * XSTR + t * 24 + l4 * 8]);
        zt[t2][0] = __builtin_amdgcn_mfma_f32_16x16x32_bf16(ax, bm0, (f32x4){0.f,0.f,0.f,0.f}, 0, 0, 0);
        zt[t2][1] = __builtin_amdgcn_mfma_f32_16x16x32_bf16(ax, bm1, (f32x4){0.f,0.f,0.f,0.f}, 0, 0, 0);
      }
      #pragma unroll
      for (int t2 = 0; t2 < 2; ++t2) {
        int t = h * 2 + t2;
        #pragma unroll
        for (int ni = 0; ni < 2; ++ni) {
          int w = ni * 16 + l15;
          if (w < 22) {
            int tw = t * 22 + w;
            int eo = tw * CHUNK + ((cb ^ (tw & 7)) << 3) + sub;
            f32x4 z = zt[t2][ni];
            u32x2 pq; pq[0] = pk_rh(z[0], z[1]); pq[1] = pk_rh(z[2], z[3]);
            *(u32x2*)(&Zw[eo]) = pq;             // 8 B aligned, ~2-way banks
          }
        }
      }
      __syncthreads();                           // wfc already drained (issued in prev main)

      // ---- main: issue wf(k+1) first (cover = this whole MFMA cluster + next z),
      //      then 24 MFMAs with wfc. out[c,tw] += Wk[c,ci-chunk] @ z. ----
      bf16x8 wfn[2][2];
      int nk = k + 1, nc = chunk;
      if (nk == 7) { nk = 0; ++nc; }
      const bool have_nxt = (nc < 4);
      if (have_nxt) load_wf(wfn, nk, nc);

      __builtin_amdgcn_s_setprio(1);
      #pragma unroll
      for (int s = 0; s < 2; ++s) {
        int cb2 = (s << 2) + l4;
        #pragma unroll
        for (int ni = 0; ni < 6; ++ni) {
          int tw = ni * 16 + l15;
          bf16x8 zf = *(const bf16x8*)(&Zw[tw * CHUNK + ((cb2 ^ (tw & 7)) << 3)]);
          #pragma unroll
          for (int mi = 0; mi < 2; ++mi)
            acc[mi][ni] = __builtin_amdgcn_mfma_f32_16x16x32_bf16(wfc[s][mi], zf, acc[mi][ni], 0, 0, 0);
        }
      }
      __builtin_amdgcn_s_setprio(0);

      if (have_nxt) {                            // rotate pipeline (register renames)
        #pragma unroll
        for (int s = 0; s < 2; ++s)
          #pragma unroll
          for (int mi = 0; mi < 2; ++mi)
            wfc[s][mi] = wfn[s][mi];
      }
      p ^= 1;                                    // next z writes the other buffer
    }
  }
  __syncthreads();                               // full drain before B2 overwrites

  // ---- bias2[c][w] = sum_k b[k*256+c] * S_k[w]  (Xs+Zs0 dead -> reuse) ----
  for (int i = tid; i < 256 * 22; i += 512) {
    int cl = i / 22, w = i - cl * 22;
    float s = 0.f;
    #pragma unroll
    for (int k = 0; k < 7; ++k) s += b[k * 256 + cl] * Ss[k * 24 + w];
    B2[cl * 25 + w] = s;
  }
  __syncthreads();

  // ---- epilogue: bias + store. C-layout: col=tw, row=l4*4+r ----
  int tg0 = tt * TT;
  #pragma unroll
  for (int ni = 0; ni < 6; ++ni) {
    int tw = ni * 16 + l15;
    if (tw < NTW) {
      int t = tw / 22, w = tw - t * 22;
      #pragma unroll
      for (int mi = 0; mi < 2; ++mi) {
        int c0 = wave * 32 + mi * 16 + l4 * 4;
        #pragma unroll
        for (int r = 0; r < 4; ++r) {
          int c = c0 + r;
          out[(size_t)((n * 256 + c) * 512 + tg0 + t) * 22 + w] = acc[mi][ni][r] + B2[c * 25 + w];
        }
      }
    }
  }
}

extern "C" void kernel_launch(void* const* d_in, const int* in_sizes, int n_in,
                              void* d_out, int out_size, void* d_ws, size_t ws_size,
                              hipStream_t stream) {
  (void)in_sizes; (void)n_in; (void)out_size;
  const float* x    = (const float*)d_in[0];
  const float* Ag   = (const float*)d_in[1];
  const float* attA = (const float*)d_in[2];
  const float* W    = (const float*)d_in[3];
  const float* b    = (const float*)d_in[4];
  float* out = (float*)d_out;
  dim3 grid(1024);         // flat = n + 8*tt  (XCD == n)
  bool use_wb = (d_ws != nullptr) && (ws_size >= (size_t)WB_BYTES);
  if (use_wb) {
    unsigned short* Wb = (unsigned short*)d_ws;
    wconv<<<224, 256, 0, stream>>>(W, Wb);
    sgc_fused<true><<<grid, 512, 0, stream>>>(x, Ag, attA, W, Wb, b, out);
  } else {
    sgc_fused<false><<<grid, 512, 0, stream>>>(x, Ag, attA, W, nullptr, b, out);
  }
}

// Round 8
// 319.340 us; speedup vs baseline: 1.1353x; 1.1353x over previous
//
#include <hip/hip_runtime.h>

// S_GC_att_A round 12: R9 (169us, best) + register-NEUTRAL wf pipelining + setprio.
// R11 post-mortem (248us): wfn[2][2]+wfc[2][2]=32 live regs -> spill (FETCH 55->219MB,
// WRITE 101->201MB). 3rd confirmation: ~16 spare VGPRs in this structure, no more.
// R12: wf consumed in two 8-reg halves (s=0 feeds first 12 MFMAs, s=1 last 12).
// After the s=0 cluster wf0 is DEAD -> load next iter's s=0 half into the same
// registers (cover to drain: 12 MFMA + z(k+1) ~600cyc); after s=1 cluster reload
// wf1 (cover: z(k+1)). Peak live wf regs = 16 == R9. Prologue (0,0) covered by
// chunk-0 staging; k=6 -> next chunk covered by staging+barrier. __syncthreads
// everywhere (R10 race class stays dead). setprio(1) around the two pure-MFMA
// clusters (T5, clean test on passing structure: z/main dbuf = real phase diversity).
// Tripwires: FETCH>80MB or WRITE>115MB => spill => strip split-loads, keep setprio.

#define TT    4
#define NTW   88     // TT*22
#define XSTR  104    // Xs row stride in bf16 (4*24 + 8 pad)
#define MROWS 176    // 7*24 + 8 pad rows
#define CHUNK 64
#define WB_BYTES (7 * 256 * 256 * 2)

typedef __attribute__((ext_vector_type(8))) __bf16    bf16x8;
typedef __attribute__((ext_vector_type(4))) float     f32x4;
typedef __attribute__((ext_vector_type(8))) short     s16x8;
typedef __attribute__((ext_vector_type(2))) unsigned  u32x2;
typedef __attribute__((ext_vector_type(4))) unsigned  u32x4;

__device__ __forceinline__ unsigned short f2bf_rn(float f) {  // RNE
  union { float f; unsigned u; } x; x.f = f;
  return (unsigned short)((x.u + 0x7FFFu + ((x.u >> 16) & 1u)) >> 16);
}
__device__ __forceinline__ unsigned pk_rh(float a, float b) { // lo=bf(a), hi=bf(b), half-up
  unsigned ua = __builtin_bit_cast(unsigned, a) + 0x8000u;
  unsigned ub = __builtin_bit_cast(unsigned, b) + 0x8000u;
  return __builtin_amdgcn_perm(ub, ua, 0x07060302);           // one v_perm_b32
}

// ---- W fp32 -> bf16 (RNE) into workspace; 224*256*8 = 458752 elems exact
__global__ void wconv(const float* __restrict__ W, unsigned short* __restrict__ Wb) {
  int i = (blockIdx.x * 256 + threadIdx.x) * 8;
  float4 a = *(const float4*)(W + i);
  float4 c = *(const float4*)(W + i + 4);
  s16x8 r;
  r[0] = (short)f2bf_rn(a.x); r[1] = (short)f2bf_rn(a.y);
  r[2] = (short)f2bf_rn(a.z); r[3] = (short)f2bf_rn(a.w);
  r[4] = (short)f2bf_rn(c.x); r[5] = (short)f2bf_rn(c.y);
  r[6] = (short)f2bf_rn(c.z); r[7] = (short)f2bf_rn(c.w);
  *(s16x8*)(Wb + i) = r;
}

__device__ __forceinline__ bf16x8 ldw_f32(const float* p) {   // fallback path
  float4 a = *(const float4*)(p);
  float4 c = *(const float4*)(p + 4);
  u32x4 q;
  q[0] = pk_rh(a.x, a.y); q[1] = pk_rh(a.z, a.w);
  q[2] = pk_rh(c.x, c.y); q[3] = pk_rh(c.z, c.w);
  return __builtin_bit_cast(bf16x8, q);
}

template <bool USE_WB>
__global__ __launch_bounds__(512, 4)
void sgc_fused(const float* __restrict__ x, const float* __restrict__ Ag,
               const float* __restrict__ attA, const float* __restrict__ W,
               const unsigned short* __restrict__ Wb, const float* __restrict__ b,
               float* __restrict__ out) {
  const int bx   = blockIdx.x;
  const int n    = bx & 7;            // XCD == n (x-tile L2 sharing across tt)
  const int tt   = bx >> 3;           // 0..127  (t-tile of 4)
  const int tid  = threadIdx.x;
  const int wave = tid >> 6;          // 0..7
  const int lane = tid & 63;
  const int l15  = lane & 15;
  const int l4   = lane >> 4;
  const int g    = wave & 3;          // z-phase ci-group
  const int h    = wave >> 2;         // z-phase t-half

  // LDS: Xs [64][104] bf16 @0 (13312) | Zs0 [96][64] swz @13312 (12288)
  //      Zs1 @25600 (12288) | Ms [176][32] bf16 @37888 (11264) | Ss @49152 (672)
  //      total 49824 B; 2 blocks/CU -> 99.6KB < 160KB
  __shared__ __align__(16) char smem[49824];
  unsigned short* Xs  = (unsigned short*)(smem);
  unsigned short* Zs0 = (unsigned short*)(smem + 13312);
  unsigned short* Zs1 = (unsigned short*)(smem + 25600);
  unsigned short* Ms  = (unsigned short*)(smem + 37888);
  float*          Ss  = (float*)(smem + 49152);
  float*          B2  = (float*)(smem);          // epilogue reuse: [256][25] f32 = 25600 B
                                                 // (covers Xs+Zs0; last main reads Zs1 - disjoint)

  f32x4 acc[2][6];                               // 48 AGPRs
  #pragma unroll
  for (int i = 0; i < 2; ++i)
    #pragma unroll
    for (int j = 0; j < 6; ++j)
      acc[i][j] = (f32x4){0.f, 0.f, 0.f, 0.f};

  auto load_wf_half = [&](bf16x8 (&wfh)[2], int kk, int cc, int s) {
    #pragma unroll
    for (int mi = 0; mi < 2; ++mi) {
      int c = wave * 32 + mi * 16 + l15;
      size_t idx = (size_t)((kk * 256 + c) * 256) + cc * CHUNK + s * 32 + l4 * 8;
      wfh[mi] = USE_WB ? *(const bf16x8*)(Wb + idx) : ldw_f32(W + idx);
    }
  };

  // ---- block init: M~[k][w][v] = M_k[v][w] bf16, zero-padded ----
  for (int i = tid; i < MROWS * 32; i += 512) {
    int row = i >> 5, v = i & 31;
    int k = row / 24, w = row - k * 24;
    float val = 0.f;
    if (row < 168 && w < 22 && v < 22)
      val = (k < 3) ? Ag[(k * 22 + v) * 22 + w]
                    : attA[(((n << 2) + (k - 3)) * 22 + v) * 22 + w];
    Ms[i] = f2bf_rn(val);
  }
  if (tid < 168) {                               // S[k][w] = sum_v M_k[v][w] (fp32 exact)
    int k = tid / 24, w = tid - k * 24;
    float s = 0.f;
    if (w < 22)
      for (int v = 0; v < 22; ++v)
        s += (k < 3) ? Ag[(k * 22 + v) * 22 + w]
                     : attA[(((n << 2) + (k - 3)) * 22 + v) * 22 + w];
    Ss[tid] = s;
  }
  Zs0[88 * CHUNK + tid] = 0;                     // pad rows 88..95, both buffers
  Zs1[88 * CHUNK + tid] = 0;
  for (int i = tid; i < 64 * XSTR / 2; i += 512) ((unsigned*)Xs)[i] = 0; // pads 0, not NaN
  __syncthreads();

  const int ci0 = g * 16 + l4 * 4;               // z-output row this thread owns
  const int cb  = ci0 >> 3, sub = ci0 & 7;
  int p = 0;                                     // Zs parity

  // ---- wf pipeline prologue: (chunk0,k0) halves issued here; covered by
  //      the whole chunk-0 staging before their drain at the staging barrier.
  bf16x8 wf0[2], wf1[2];
  load_wf_half(wf0, 0, 0, 0);
  load_wf_half(wf1, 0, 0, 1);

  for (int chunk = 0; chunk < 4; ++chunk) {
    // ---- stage x[n, chunk*64..+64, tt*4..+4, :] -> Xs bf16 [ci][t*24+v] ----
    // paired u32 writes: tv pairs at even offsets never straddle a t-row (22 even).
    for (int i = tid; i < CHUNK * 22; i += 512) {
      int ci = i / 22, q = i - ci * 22;
      const float4 f4 = *(const float4*)(x + (size_t)((n * 256 + chunk * CHUNK + ci) * 11264)
                                           + tt * NTW + q * 4);
      int tv0 = q * 4;
      int t0 = tv0 / 22, v0 = tv0 - t0 * 22;
      ((unsigned*)Xs)[ci * 52 + t0 * 12 + (v0 >> 1)] = pk_rh(f4.x, f4.y);
      int tv2 = tv0 + 2;
      int t2 = tv2 / 22, v2 = tv2 - t2 * 22;
      ((unsigned*)Xs)[ci * 52 + t2 * 12 + (v2 >> 1)] = pk_rh(f4.z, f4.w);
    }
    __syncthreads();

    for (int k = 0; k < 7; ++k) {
      unsigned short* Zw = p ? Zs1 : Zs0;

      // ---- z phase: z[ci,w] = X[ci,v] @ M_k[v,w]; wave (g,h): rows [g*16,+16),
      //      t in {2h, 2h+1}. 8 waves cover all 64 ci x 4 t exactly once. ----
      bf16x8 bm0 = *(const bf16x8*)(&Ms[(k * 24 + l15) * 32 + l4 * 8]);
      bf16x8 bm1 = *(const bf16x8*)(&Ms[(k * 24 + 16 + l15) * 32 + l4 * 8]);
      f32x4 zt[2][2];
      #pragma unroll
      for (int t2 = 0; t2 < 2; ++t2) {
        int t = h * 2 + t2;
        bf16x8 ax = *(const bf16x8*)(&Xs[(g * 16 + l15) * XSTR + t * 24 + l4 * 8]);
        zt[t2][0] = __builtin_amdgcn_mfma_f32_16x16x32_bf16(ax, bm0, (f32x4){0.f,0.f,0.f,0.f}, 0, 0, 0);
        zt[t2][1] = __builtin_amdgcn_mfma_f32_16x16x32_bf16(ax, bm1, (f32x4){0.f,0.f,0.f,0.f}, 0, 0, 0);
      }
      #pragma unroll
      for (int t2 = 0; t2 < 2; ++t2) {
        int t = h * 2 + t2;
        #pragma unroll
        for (int ni = 0; ni < 2; ++ni) {
          int w = ni * 16 + l15;
          if (w < 22) {
            int tw = t * 22 + w;
            int eo = tw * CHUNK + ((cb ^ (tw & 7)) << 3) + sub;
            f32x4 z = zt[t2][ni];
            u32x2 pq; pq[0] = pk_rh(z[0], z[1]); pq[1] = pk_rh(z[2], z[3]);
            *(u32x2*)(&Zw[eo]) = pq;             // 8 B aligned, ~2-way banks
          }
        }
      }
      __syncthreads();                           // wf halves drained here were issued
                                                 // >= 1 MFMA-cluster + z-phase ago

      // ---- main GEMM: out[c,tw] += Wk[c, ci-chunk] @ z; wave owns c [wave*32,+32).
      //      Split-rotation: after s=0 cluster wf0 is dead -> refill with next
      //      iter's s=0 half; after s=1 cluster refill wf1. Peak live wf = 16 regs.
      int nk = k + 1, nc = chunk;
      if (nk == 7) { nk = 0; ++nc; }
      const bool have_nxt = (nc < 4);

      __builtin_amdgcn_s_setprio(1);
      #pragma unroll
      for (int ni = 0; ni < 6; ++ni) {
        int tw = ni * 16 + l15;
        bf16x8 zf = *(const bf16x8*)(&Zw[tw * CHUNK + ((l4 ^ (tw & 7)) << 3)]);
        #pragma unroll
        for (int mi = 0; mi < 2; ++mi)
          acc[mi][ni] = __builtin_amdgcn_mfma_f32_16x16x32_bf16(wf0[mi], zf, acc[mi][ni], 0, 0, 0);
      }
      __builtin_amdgcn_s_setprio(0);
      if (have_nxt) load_wf_half(wf0, nk, nc, 0);

      __builtin_amdgcn_s_setprio(1);
      #pragma unroll
      for (int ni = 0; ni < 6; ++ni) {
        int tw = ni * 16 + l15;
        bf16x8 zf = *(const bf16x8*)(&Zw[tw * CHUNK + (((4 + l4) ^ (tw & 7)) << 3)]);
        #pragma unroll
        for (int mi = 0; mi < 2; ++mi)
          acc[mi][ni] = __builtin_amdgcn_mfma_f32_16x16x32_bf16(wf1[mi], zf, acc[mi][ni], 0, 0, 0);
      }
      __builtin_amdgcn_s_setprio(0);
      if (have_nxt) load_wf_half(wf1, nk, nc, 1);

      p ^= 1;                                    // next z writes the other buffer
    }
  }
  __syncthreads();                               // full drain before B2 overwrites

  // ---- bias2[c][w] = sum_k b[k*256+c] * S_k[w]  (Xs+Zs0 dead -> reuse) ----
  for (int i = tid; i < 256 * 22; i += 512) {
    int cl = i / 22, w = i - cl * 22;
    float s = 0.f;
    #pragma unroll
    for (int k = 0; k < 7; ++k) s += b[k * 256 + cl] * Ss[k * 24 + w];
    B2[cl * 25 + w] = s;
  }
  __syncthreads();

  // ---- epilogue: bias + store. C-layout: col=tw, row=l4*4+r ----
  int tg0 = tt * TT;
  #pragma unroll
  for (int ni = 0; ni < 6; ++ni) {
    int tw = ni * 16 + l15;
    if (tw < NTW) {
      int t = tw / 22, w = tw - t * 22;
      #pragma unroll
      for (int mi = 0; mi < 2; ++mi) {
        int c0 = wave * 32 + mi * 16 + l4 * 4;
        #pragma unroll
        for (int r = 0; r < 4; ++r) {
          int c = c0 + r;
          out[(size_t)((n * 256 + c) * 512 + tg0 + t) * 22 + w] = acc[mi][ni][r] + B2[c * 25 + w];
        }
      }
    }
  }
}

extern "C" void kernel_launch(void* const* d_in, const int* in_sizes, int n_in,
                              void* d_out, int out_size, void* d_ws, size_t ws_size,
                              hipStream_t stream) {
  (void)in_sizes; (void)n_in; (void)out_size;
  const float* x    = (const float*)d_in[0];
  const float* Ag   = (const float*)d_in[1];
  const float* attA = (const float*)d_in[2];
  const float* W    = (const float*)d_in[3];
  const float* b    = (const float*)d_in[4];
  float* out = (float*)d_out;
  dim3 grid(1024);         // flat = n + 8*tt  (XCD == n)
  bool use_wb = (d_ws != nullptr) && (ws_size >= (size_t)WB_BYTES);
  if (use_wb) {
    unsigned short* Wb = (unsigned short*)d_ws;
    wconv<<<224, 256, 0, stream>>>(W, Wb);
    sgc_fused<true><<<grid, 512, 0, stream>>>(x, Ag, attA, W, Wb, b, out);
  } else {
    sgc_fused<false><<<grid, 512, 0, stream>>>(x, Ag, attA, W, nullptr, b, out);
  }
}